// Round 7
// baseline (555.437 us; speedup 1.0000x reference)
//
#include <hip/hip_runtime.h>
#include <hip/hip_cooperative_groups.h>
#include <math.h>

namespace cg = cooperative_groups;

#define SLOPE 0.2f

typedef short bf16x8 __attribute__((ext_vector_type(8)));
typedef float f32x4 __attribute__((ext_vector_type(4)));
typedef unsigned short u16x4 __attribute__((ext_vector_type(4)));
typedef unsigned short u16x8 __attribute__((ext_vector_type(8)));

static __device__ __forceinline__ unsigned short f2bf(float x) {
    unsigned int u = __float_as_uint(x);
    unsigned int r = (u + 0x7fffu + ((u >> 16) & 1u)) >> 16;   // RNE
    return (unsigned short)r;
}
static __device__ __forceinline__ float bf2f(unsigned short h) {
    return __uint_as_float(((unsigned int)h) << 16);
}
static __device__ __forceinline__ unsigned fenc(float f) {
    unsigned u = __float_as_uint(f);
    return (u & 0x80000000u) ? ~u : (u | 0x80000000u);
}
static __device__ __forceinline__ float fdec(unsigned u) {
    unsigned b = (u & 0x80000000u) ? (u & 0x7FFFFFFFu) : ~u;
    return __uint_as_float(b);
}

// ---- ws byte offsets ----
#define OFF_WP     0
#define OFF_X1P    6291456
#define OFF_XMP    18874368
#define OFF_X2P    31457280
#define OFF_X3P    39845888
#define OFF_X4P    44040192
#define OFF_C1     48234496
#define OFF_GLOBE  48238592
#define OFF_GBIAS  48242688
#define OFF_HACC1  48246784   // [6144][4] f32
#define OFF_HACC2  48345088   // [4096][4] f32
#define ZERO_WORDS 43008      // globE..hacc2 end

struct Params {
    const float *z, *W1a, *b1a, *W1b, *b1b, *W1c, *b1c, *Wx1, *bx1;
    const float *W2a, *b2a, *W2b, *b2b, *W2c, *b2c, *Wx2, *bx2;
    char* wsb;
    float *out0, *out1, *out2;
};

// ================= phase device functions (grid-stride, any grid) =================

static __device__ void dev_prep(const Params& p) {
    unsigned short* WP   = (unsigned short*)(p.wsb + OFF_WP);
    unsigned short* WP2a = WP + 2097152;
    float* c1 = (float*)(p.wsb + OFF_C1);
    float* zb = (float*)(p.wsb + OFF_GLOBE);
    const int t = threadIdx.x;
    const int stride = gridDim.x * 256;
    for (int idx = blockIdx.x * 256 + t; idx < 1572864; idx += stride) {
        const float* src; unsigned short* dst; int o, k, K, in_ld;
        if (idx < 1048576) {
            int which = idx >> 18; int local = idx & 262143;
            K = 512; in_ld = 512;
            src = (which == 0) ? p.W1b : (which == 1) ? p.W1c : (which == 2) ? p.W2b : p.W2c;
            dst = WP + (long)which * 524288;
            o = local >> 9; k = local & 511;
        } else {
            int local = idx - 1048576;
            K = 1024; in_ld = 1536; src = p.W2a; dst = WP2a;
            o = local >> 10; k = local & 1023;
        }
        float v = src[(long)o * in_ld + k];
        unsigned short hi = f2bf(v);
        dst[(long)o * 2 * K + k] = hi;
        dst[(long)o * 2 * K + K + k] = f2bf(v - bf2f(hi));
    }
    for (int l = blockIdx.x * 256 + t; l < ZERO_WORDS; l += stride) zb[l] = 0.f;
    const int lane = t & 63;
    for (int gid = blockIdx.x * 4 + (t >> 6); gid < 1024; gid += gridDim.x * 4) {
        int b = gid >> 9, o = gid & 511;
        float acc = 0.f;
        const float* wr = p.W1a + (long)o * 514;
        const float* zv = p.z + b * 512;
        for (int k = lane; k < 512; k += 64) acc += wr[k] * zv[k];
        #pragma unroll
        for (int off = 32; off > 0; off >>= 1) acc += __shfl_down(acc, off, 64);
        if (lane == 0) c1[gid] = acc + p.b1a[o];
    }
}

static __device__ void dev_layer_a(const Params& p) {
    unsigned short* X1P = (unsigned short*)(p.wsb + OFF_X1P);
    const float* c1 = (const float*)(p.wsb + OFF_C1);
    const int stride = gridDim.x * 256;
    for (int idx = blockIdx.x * 256 + threadIdx.x; idx < 3145728; idx += stride) {
        int o = idx & 511;
        int r = idx >> 9;
        int b, n, side;
        if (r < 2048) { b = r >> 10; n = r & 1023; side = 32; }
        else          { int r2 = r - 2048; b = r2 >> 11; n = r2 & 2047; side = 46; }
        int row = n / side, col = n % side;
        double inv = 1.0 / (double)(side - 1);
        float lx = (row == side - 1) ? 1.0f : (float)(row * inv);
        float ly = (col == side - 1) ? 1.0f : (float)(col * inv);
        float h = c1[b * 512 + o] + p.W1a[(long)o * 514 + 512] * lx
                                  + p.W1a[(long)o * 514 + 513] * ly;
        h = (h > 0.f) ? h : SLOPE * h;
        unsigned short hi = f2bf(h);
        X1P[(long)r * 1024 + o] = hi;
        X1P[(long)r * 1024 + 512 + o] = f2bf(h - bf2f(hi));
    }
}

// ---------------- one GEMM tile: 64(o) x 32J(n), TERMS=3 split-bf16 / TERMS=1 bf16 ----
template<int TERMS, int J>
static __device__ void dev_gemm_tile(char* sm, int t, int tile,
    const unsigned short* __restrict__ Wp, int ldw,
    const unsigned short* __restrict__ Xp, int ldx, int K,
    const float* __restrict__ bias, bool biasPerB,
    unsigned short* __restrict__ Xn, int ldxn, int lo_off, int row_off, int pack_min,
    const float* __restrict__ Wx, float* __restrict__ hacc,
    unsigned* __restrict__ globE) {

    constexpr int NT = 32 * J;
    constexpr int NSA = (TERMS == 3) ? 4 : 2;
    constexpr int NSB = (TERMS == 3) ? (2 * J) : J;
    constexpr int NSLOT = NSA + NSB;

    const int nb0 = (tile & 63) * NT;
    const int ob0 = (tile >> 6) * 64;

    const unsigned short* gp[NSLOT];
    int lo_[NSLOT];
    #pragma unroll
    for (int s = 0; s < NSA; ++s) {
        int half = s >> 1, part = s & 1;
        int j2 = (part << 8) + t;
        int r = j2 >> 3, cl = j2 & 7, cs = cl ^ (r & 7);
        gp[s] = Wp + (long)(ob0 + r) * ldw + half * K + cs * 8;
        lo_[s] = half * 8192 + j2 * 16;
    }
    #pragma unroll
    for (int s = 0; s < NSB; ++s) {
        int half = (TERMS == 3) ? (s / J) : 0;
        int part = (TERMS == 3) ? (s % J) : s;
        int j2 = (part << 8) + t;
        int r = j2 >> 3, cl = j2 & 7, cs = cl ^ (r & 7);
        gp[NSA + s] = Xp + (long)(nb0 + r) * ldx + half * K + cs * 8;
        lo_[NSA + s] = 16384 + half * (4096 * J) + j2 * 16;
    }

    const int lane = t & 63, w = t >> 6;
    const int wy = w >> 1, wx = w & 1;
    const int quad = lane >> 4, l15 = lane & 15;
    const int rowA = (wy * 32 + l15) * 128;
    const int ca0 = (quad ^ (l15 & 7)) * 16;
    const int ca1 = ((quad + 4) ^ (l15 & 7)) * 16;

    f32x4 acc[2][J];
    #pragma unroll
    for (int i = 0; i < 2; ++i)
        #pragma unroll
        for (int j = 0; j < J; ++j) { f32x4 zz = {0.f, 0.f, 0.f, 0.f}; acc[i][j] = zz; }

    for (int k0 = 0; k0 < K; k0 += 64) {
        #pragma unroll
        for (int s = 0; s < NSLOT; ++s)
            __builtin_amdgcn_global_load_lds(
                (const __attribute__((address_space(1))) void*)(const void*)(gp[s] + k0),
                (__attribute__((address_space(3))) void*)(void*)(sm + lo_[s]),
                16, 0, 0);
        __syncthreads();
        #pragma unroll
        for (int sub = 0; sub < 2; ++sub) {
            const int cb = (sub == 0) ? ca0 : ca1;
            bf16x8 ah[2], bh[J];
            #pragma unroll
            for (int i = 0; i < 2; ++i)
                ah[i] = *(const bf16x8*)(const void*)(sm + rowA + i * 2048 + cb);
            #pragma unroll
            for (int j = 0; j < J; ++j)
                bh[j] = *(const bf16x8*)(const void*)(sm + 16384 + (wx * 16 * J + j * 16 + l15) * 128 + cb);
            if (TERMS == 3) {
                bf16x8 al[2], bl[J];
                #pragma unroll
                for (int i = 0; i < 2; ++i)
                    al[i] = *(const bf16x8*)(const void*)(sm + 8192 + rowA + i * 2048 + cb);
                #pragma unroll
                for (int j = 0; j < J; ++j)
                    bl[j] = *(const bf16x8*)(const void*)(sm + 16384 + 4096 * J + (wx * 16 * J + j * 16 + l15) * 128 + cb);
                #pragma unroll
                for (int i = 0; i < 2; ++i)
                    #pragma unroll
                    for (int j = 0; j < J; ++j) {
                        acc[i][j] = __builtin_amdgcn_mfma_f32_16x16x32_bf16(ah[i], bh[j], acc[i][j], 0, 0, 0);
                        acc[i][j] = __builtin_amdgcn_mfma_f32_16x16x32_bf16(ah[i], bl[j], acc[i][j], 0, 0, 0);
                        acc[i][j] = __builtin_amdgcn_mfma_f32_16x16x32_bf16(al[i], bh[j], acc[i][j], 0, 0, 0);
                    }
            } else {
                #pragma unroll
                for (int i = 0; i < 2; ++i)
                    #pragma unroll
                    for (int j = 0; j < J; ++j)
                        acc[i][j] = __builtin_amdgcn_mfma_f32_16x16x32_bf16(ah[i], bh[j], acc[i][j], 0, 0, 0);
            }
        }
        __syncthreads();
    }

    // epilogue
    float val[2][J][4];
    #pragma unroll
    for (int j = 0; j < J; ++j) {
        int n = nb0 + wx * 16 * J + j * 16 + l15;
        int bofs = biasPerB ? ((n >> 11) * 512) : 0;
        #pragma unroll
        for (int i = 0; i < 2; ++i) {
            int ob = ob0 + wy * 32 + i * 16 + quad * 4;
            #pragma unroll
            for (int r = 0; r < 4; ++r) {
                float x = acc[i][j][r] + bias[bofs + ob + r];
                val[i][j][r] = (x > 0.f) ? x : SLOPE * x;
            }
        }
        if (Xn && n >= pack_min) {
            long nl = n - row_off;
            #pragma unroll
            for (int i = 0; i < 2; ++i) {
                int ob = ob0 + wy * 32 + i * 16 + quad * 4;
                u16x4 h4;
                #pragma unroll
                for (int r = 0; r < 4; ++r) h4[r] = f2bf(val[i][j][r]);
                *(u16x4*)(void*)(Xn + nl * ldxn + ob) = h4;
                if (lo_off) {
                    u16x4 l4;
                    #pragma unroll
                    for (int r = 0; r < 4; ++r) l4[r] = f2bf(val[i][j][r] - bf2f(h4[r]));
                    *(u16x4*)(void*)(Xn + nl * ldxn + lo_off + ob) = l4;
                }
            }
        }
    }

    if (hacc) {
        __syncthreads();
        float* smh = (float*)sm;                 // [NT][4]
        unsigned* smg = (unsigned*)(sm + 2048);  // [2][64]
        for (int l = t; l < NT * 4; l += 256) smh[l] = 0.f;
        if (t < 128) smg[t] = 0u;
        __syncthreads();
        float wxv[3][2][4];
        #pragma unroll
        for (int ch = 0; ch < 3; ++ch)
            #pragma unroll
            for (int i = 0; i < 2; ++i)
                #pragma unroll
                for (int r = 0; r < 4; ++r)
                    wxv[ch][i][r] = Wx[ch * 512 + ob0 + wy * 32 + i * 16 + quad * 4 + r];
        #pragma unroll
        for (int j = 0; j < J; ++j) {
            int nl = wx * 16 * J + j * 16 + l15;
            int n = nb0 + nl;
            float p0 = 0.f, p1 = 0.f, p2 = 0.f;
            #pragma unroll
            for (int i = 0; i < 2; ++i)
                #pragma unroll
                for (int r = 0; r < 4; ++r) {
                    float v = val[i][j][r];
                    p0 += v * wxv[0][i][r];
                    p1 += v * wxv[1][i][r];
                    p2 += v * wxv[2][i][r];
                }
            atomicAdd(&smh[nl * 4 + 0], p0);
            atomicAdd(&smh[nl * 4 + 1], p1);
            atomicAdd(&smh[nl * 4 + 2], p2);
            if (globE && n >= 2048) {
                int bsel = (n >= 4096) ? 1 : 0;
                #pragma unroll
                for (int i = 0; i < 2; ++i)
                    #pragma unroll
                    for (int r = 0; r < 4; ++r)
                        atomicMax(&smg[bsel * 64 + wy * 32 + i * 16 + quad * 4 + r],
                                  fenc(val[i][j][r]));
            }
        }
        __syncthreads();
        if (t < NT) {
            atomicAdd(&hacc[(long)(nb0 + t) * 4 + 0], smh[t * 4 + 0]);
            atomicAdd(&hacc[(long)(nb0 + t) * 4 + 1], smh[t * 4 + 1]);
            atomicAdd(&hacc[(long)(nb0 + t) * 4 + 2], smh[t * 4 + 2]);
        }
        if (globE && t < 128)
            atomicMax(&globE[(t >> 6) * 512 + ob0 + (t & 63)], smg[t]);
        __syncthreads();
    }
}

static __device__ void dev_fin1(const Params& p) {
    const float* hacc1 = (const float*)(p.wsb + OFF_HACC1);
    const unsigned* globE = (const unsigned*)(p.wsb + OFF_GLOBE);
    float* gbias = (float*)(p.wsb + OFF_GBIAS);
    const int t = threadIdx.x;
    for (int r = blockIdx.x * 256 + t; r < 6144; r += gridDim.x * 256) {
        float* dst = (r < 2048) ? (p.out0 + (long)r * 3) : (p.out2 + (long)(r - 2048) * 3);
        #pragma unroll
        for (int ch = 0; ch < 3; ++ch) {
            float a = hacc1[(long)r * 4 + ch] + p.bx1[ch];
            dst[ch] = 1.f / (1.f + expf(-a)) - 0.5f;
        }
    }
    const int lane = t & 63;
    for (int gid = blockIdx.x * 4 + (t >> 6); gid < 1024; gid += gridDim.x * 4) {
        int b = gid >> 9, o = gid & 511;
        float acc = 0.f;
        const float* wr = p.W2a + (long)o * 1536 + 1024;
        for (int k = lane; k < 512; k += 64) acc += wr[k] * fdec(globE[b * 512 + k]);
        #pragma unroll
        for (int off = 32; off > 0; off >>= 1) acc += __shfl_down(acc, off, 64);
        if (lane == 0) gbias[gid] = acc + p.b2a[o];
    }
}

static __device__ void dev_ball(char* sm, int i, int b, int t,
                                const float* __restrict__ fine,
                                unsigned short* __restrict__ X2P) {
    int lane = t & 63, wv = t >> 6;
    int* idxl = (int*)sm;                 // 64 ints
    int* wcnt = (int*)(sm + 256);         // 4 ints
    float* part = (float*)(sm + 512);     // [8][256]
    const float* fb = fine + (long)b * 2048 * 3;
    float xi = fb[i * 3 + 0], yi = fb[i * 3 + 1], zi = fb[i * 3 + 2];
    float sqi = __fadd_rn(__fadd_rn(__fmul_rn(xi, xi), __fmul_rn(yi, yi)), __fmul_rn(zi, zi));
    int cnt = 0;
    for (int it = 0; it < 8; ++it) {
        int j = it * 256 + t;
        float xj = fb[j * 3 + 0], yj = fb[j * 3 + 1], zj = fb[j * 3 + 2];
        float sqj = __fadd_rn(__fadd_rn(__fmul_rn(xj, xj), __fmul_rn(yj, yj)), __fmul_rn(zj, zj));
        float dot = __fadd_rn(__fadd_rn(__fmul_rn(xi, xj), __fmul_rn(yi, yj)), __fmul_rn(zi, zj));
        float d2 = __fsub_rn(__fadd_rn(sqi, sqj), __fmul_rn(2.0f, dot));
        bool pred = d2 < 0.01f;
        unsigned long long m = __ballot(pred);
        if (lane == 0) wcnt[wv] = __popcll(m);
        __syncthreads();
        int wbase = cnt;
        #pragma unroll
        for (int q = 0; q < 3; ++q) { if (q < wv) wbase += wcnt[q]; }
        int total = wcnt[0] + wcnt[1] + wcnt[2] + wcnt[3];
        int rank = wbase + __popcll(m & ((1ull << lane) - 1ull));
        if (pred && rank < 64) idxl[rank] = j;
        cnt += total;
        if (cnt >= 64) break;       // uniform across block
        __syncthreads();
    }
    __syncthreads();
    int m = min(cnt, 64);

    const unsigned short* hb = X2P + (long)b * 2048 * 1024;
    int g = t & 63, q = t >> 6;
    float mx[8];
    #pragma unroll
    for (int r = 0; r < 8; ++r) mx[r] = -1e30f;
    for (int jj = q; jj < m; jj += 4) {
        u16x8 v = *(const u16x8*)(const void*)(hb + (long)idxl[jj] * 1024 + g * 8);
        #pragma unroll
        for (int r = 0; r < 8; ++r) mx[r] = fmaxf(mx[r], bf2f(v[r]));
    }
    #pragma unroll
    for (int r = 0; r < 8; ++r) part[r * 256 + t] = mx[r];
    __syncthreads();
    if (t < 64) {
        unsigned short* orow = X2P + (long)(b * 2048 + i) * 1024;
        u16x8 hi;
        #pragma unroll
        for (int r = 0; r < 8; ++r) {
            float v0 = fmaxf(fmaxf(part[r * 256 + t], part[r * 256 + t + 64]),
                             fmaxf(part[r * 256 + t + 128], part[r * 256 + t + 192]));
            hi[r] = (unsigned short)(__float_as_uint(v0) >> 16);   // exact: bf16-valued
        }
        *(u16x8*)(void*)(orow + 512 + t * 8) = hi;
    }
    __syncthreads();
}

static __device__ void dev_fin2(const Params& p) {
    const float* hacc2 = (const float*)(p.wsb + OFF_HACC2);
    for (int r = blockIdx.x * 256 + threadIdx.x; r < 4096; r += gridDim.x * 256) {
        #pragma unroll
        for (int ch = 0; ch < 3; ++ch) {
            float a = hacc2[(long)r * 4 + ch] + p.bx2[ch];
            p.out1[(long)r * 3 + ch] = p.out2[(long)r * 3 + ch]
                                     + 0.1f * (1.f / (1.f + expf(-a)) - 0.5f);
        }
    }
}

// ================= GEMM arg helper macros (shared by mega + fallback) =================
#define WPB(wsb)  ((unsigned short*)((wsb) + OFF_WP))
#define GEMM1B_ARGS(p) WPB(p.wsb), 1024, (unsigned short*)(p.wsb + OFF_X1P), 1024, 512, p.b1b, false, \
                       (unsigned short*)(p.wsb + OFF_XMP), 1024, 512, 0, 0, nullptr, nullptr, nullptr
#define GEMM1C_ARGS(p) WPB(p.wsb) + 524288, 1024, (unsigned short*)(p.wsb + OFF_XMP), 1024, 512, p.b1c, false, \
                       (unsigned short*)(p.wsb + OFF_X2P), 1024, 0, 2048, 2048, p.Wx1, \
                       (float*)(p.wsb + OFF_HACC1), (unsigned*)(p.wsb + OFF_GLOBE)
#define GEMM2A_ARGS(p) WPB(p.wsb) + 2097152, 2048, (unsigned short*)(p.wsb + OFF_X2P), 1024, 1024, \
                       (const float*)(p.wsb + OFF_GBIAS), true, \
                       (unsigned short*)(p.wsb + OFF_X3P), 512, 0, 0, 0, nullptr, nullptr, nullptr
#define GEMM2B_ARGS(p) WPB(p.wsb) + 1048576, 1024, (unsigned short*)(p.wsb + OFF_X3P), 512, 512, p.b2b, false, \
                       (unsigned short*)(p.wsb + OFF_X4P), 512, 0, 0, 0, nullptr, nullptr, nullptr
#define GEMM2C_ARGS(p) WPB(p.wsb) + 1572864, 1024, (unsigned short*)(p.wsb + OFF_X4P), 512, 512, p.b2c, false, \
                       (unsigned short*)nullptr, 0, 0, 0, 0, p.Wx2, (float*)(p.wsb + OFF_HACC2), (unsigned*)nullptr

// ================= cooperative mega-kernel =================
__global__ __launch_bounds__(256, 2) void mega(Params p) {
    cg::grid_group grid = cg::this_grid();
    const int t = threadIdx.x;
    const int G = gridDim.x;
    __shared__ __align__(16) char sm[40960];

    dev_prep(p);
    grid.sync();
    dev_layer_a(p);
    grid.sync();
    for (int tile = blockIdx.x; tile < 512; tile += G)
        dev_gemm_tile<3, 3>(sm, t, tile, GEMM1B_ARGS(p));
    grid.sync();
    for (int tile = blockIdx.x; tile < 512; tile += G)
        dev_gemm_tile<3, 3>(sm, t, tile, GEMM1C_ARGS(p));
    grid.sync();
    dev_fin1(p);
    grid.sync();
    for (int task = blockIdx.x; task < 4096; task += G)
        dev_ball(sm, task & 2047, task >> 11, t, p.out2, (unsigned short*)(p.wsb + OFF_X2P));
    grid.sync();
    for (int tile = blockIdx.x; tile < 512; tile += G)
        dev_gemm_tile<1, 2>(sm, t, tile, GEMM2A_ARGS(p));
    grid.sync();
    for (int tile = blockIdx.x; tile < 512; tile += G)
        dev_gemm_tile<1, 2>(sm, t, tile, GEMM2B_ARGS(p));
    grid.sync();
    for (int tile = blockIdx.x; tile < 512; tile += G)
        dev_gemm_tile<1, 2>(sm, t, tile, GEMM2C_ARGS(p));
    grid.sync();
    dev_fin2(p);
}

// ================= fallback wrappers (independent dispatches) =================
__global__ void g_prep(Params p)    { dev_prep(p); }
__global__ void g_layer_a(Params p) { dev_layer_a(p); }
__global__ void g_fin1(Params p)    { dev_fin1(p); }
__global__ void g_fin2(Params p)    { dev_fin2(p); }
__global__ __launch_bounds__(256) void g_ball(Params p) {
    __shared__ __align__(16) char sm[9216];
    for (int task = blockIdx.x; task < 4096; task += gridDim.x)
        dev_ball(sm, task & 2047, task >> 11, threadIdx.x, p.out2,
                 (unsigned short*)(p.wsb + OFF_X2P));
}
__global__ __launch_bounds__(256, 2) void g_gemm1b(Params p) {
    __shared__ __align__(16) char sm[40960];
    for (int tile = blockIdx.x; tile < 512; tile += gridDim.x)
        dev_gemm_tile<3, 3>(sm, threadIdx.x, tile, GEMM1B_ARGS(p));
}
__global__ __launch_bounds__(256, 2) void g_gemm1c(Params p) {
    __shared__ __align__(16) char sm[40960];
    for (int tile = blockIdx.x; tile < 512; tile += gridDim.x)
        dev_gemm_tile<3, 3>(sm, threadIdx.x, tile, GEMM1C_ARGS(p));
}
__global__ __launch_bounds__(256, 2) void g_gemm2a(Params p) {
    __shared__ __align__(16) char sm[40960];
    for (int tile = blockIdx.x; tile < 512; tile += gridDim.x)
        dev_gemm_tile<1, 2>(sm, threadIdx.x, tile, GEMM2A_ARGS(p));
}
__global__ __launch_bounds__(256, 2) void g_gemm2b(Params p) {
    __shared__ __align__(16) char sm[40960];
    for (int tile = blockIdx.x; tile < 512; tile += gridDim.x)
        dev_gemm_tile<1, 2>(sm, threadIdx.x, tile, GEMM2B_ARGS(p));
}
__global__ __launch_bounds__(256, 2) void g_gemm2c(Params p) {
    __shared__ __align__(16) char sm[40960];
    for (int tile = blockIdx.x; tile < 512; tile += gridDim.x)
        dev_gemm_tile<1, 2>(sm, threadIdx.x, tile, GEMM2C_ARGS(p));
}

// ================= launch =================
extern "C" void kernel_launch(void* const* d_in, const int* in_sizes, int n_in,
                              void* d_out, int out_size, void* d_ws, size_t ws_size,
                              hipStream_t stream) {
    Params p;
    p.z   = (const float*)d_in[0];
    p.W1a = (const float*)d_in[1];
    p.b1a = (const float*)d_in[2];
    p.W1b = (const float*)d_in[3];
    p.b1b = (const float*)d_in[4];
    p.W1c = (const float*)d_in[5];
    p.b1c = (const float*)d_in[6];
    p.Wx1 = (const float*)d_in[7];
    p.bx1 = (const float*)d_in[8];
    p.W2a = (const float*)d_in[9];
    p.b2a = (const float*)d_in[10];
    p.W2b = (const float*)d_in[11];
    p.b2b = (const float*)d_in[12];
    p.W2c = (const float*)d_in[13];
    p.b2c = (const float*)d_in[14];
    p.Wx2 = (const float*)d_in[15];
    p.bx2 = (const float*)d_in[16];
    p.wsb = (char*)d_ws;
    p.out0 = (float*)d_out;              // (2,1024,3)
    p.out1 = p.out0 + 2 * 1024 * 3;      // (2,2048,3)
    p.out2 = p.out1 + 2 * 2048 * 3;      // (2,2048,3) fine_points

    // size cooperative grid to true occupancy, then verify the launch is accepted
    int maxPerCU = 0;
    hipError_t qe = hipOccupancyMaxActiveBlocksPerMultiprocessor(&maxPerCU, mega, 256, 0);
    int G = (qe == hipSuccess) ? maxPerCU * 256 : 0;
    if (G > 512) G = 512;
    bool coop_ok = false;
    if (G >= 256) {
        void* args[] = { (void*)&p };
        coop_ok = (hipLaunchCooperativeKernel((const void*)mega, dim3(G), dim3(256),
                                              args, 0, stream) == hipSuccess);
    }
    if (!coop_ok) {
        g_prep<<<2048, 256, 0, stream>>>(p);
        g_layer_a<<<2048, 256, 0, stream>>>(p);
        g_gemm1b<<<512, 256, 0, stream>>>(p);
        g_gemm1c<<<512, 256, 0, stream>>>(p);
        g_fin1<<<512, 256, 0, stream>>>(p);
        g_ball<<<4096, 256, 0, stream>>>(p);
        g_gemm2a<<<512, 256, 0, stream>>>(p);
        g_gemm2b<<<512, 256, 0, stream>>>(p);
        g_gemm2c<<<512, 256, 0, stream>>>(p);
        g_fin2<<<16, 256, 0, stream>>>(p);
    }
}

// Round 8
// 259.213 us; speedup vs baseline: 2.1428x; 2.1428x over previous
//
#include <hip/hip_runtime.h>
#include <math.h>

#define SLOPE 0.2f

typedef short bf16x8 __attribute__((ext_vector_type(8)));
typedef float f32x4 __attribute__((ext_vector_type(4)));
typedef unsigned short u16x4 __attribute__((ext_vector_type(4)));
typedef unsigned short u16x8 __attribute__((ext_vector_type(8)));

static __device__ __forceinline__ unsigned short f2bf(float x) {
    unsigned int u = __float_as_uint(x);
    unsigned int r = (u + 0x7fffu + ((u >> 16) & 1u)) >> 16;   // RNE
    return (unsigned short)r;
}
static __device__ __forceinline__ float bf2f(unsigned short h) {
    return __uint_as_float(((unsigned int)h) << 16);
}
static __device__ __forceinline__ unsigned fenc(float f) {
    unsigned u = __float_as_uint(f);
    return (u & 0x80000000u) ? ~u : (u | 0x80000000u);
}
static __device__ __forceinline__ float fdec(unsigned u) {
    unsigned b = (u & 0x80000000u) ? (u & 0x7FFFFFFFu) : ~u;
    return __uint_as_float(b);
}

// ---- ws byte offsets ----
#define OFF_WP     0
#define OFF_X1P    6291456
#define OFF_XMP    18874368
#define OFF_X2P    31457280
#define OFF_X3P    39845888
#define OFF_X4P    44040192
#define OFF_C1     48234496
#define OFF_GLOBE  48238592
#define OFF_GBIAS  48242688
#define OFF_HACC1  48246784   // [6144][4] f32
#define OFF_HACC2  48345088   // [4096][4] f32
#define OFF_CNT    48410624   // counters
#define ZERO_WORDS 43024      // globE..cnt end, in f32 words

struct Params {
    const float *z, *W1a, *b1a, *W1b, *b1b, *W1c, *b1c, *Wx1, *bx1;
    const float *W2a, *b2a, *W2b, *b2b, *W2c, *b2c, *Wx2, *bx2;
    char* wsb;
    float *out0, *out1, *out2;
};

// ================= prep: pack weights + zero accumulators + c1 GEMV =================
__global__ void g_prep(Params p) {
    unsigned short* WP   = (unsigned short*)(p.wsb + OFF_WP);
    unsigned short* WP2a = WP + 2097152;
    float* c1 = (float*)(p.wsb + OFF_C1);
    float* zb = (float*)(p.wsb + OFF_GLOBE);
    const int t = threadIdx.x;
    const int stride = gridDim.x * 256;
    for (int idx = blockIdx.x * 256 + t; idx < 1572864; idx += stride) {
        const float* src; unsigned short* dst; int o, k, K, in_ld;
        if (idx < 1048576) {
            int which = idx >> 18; int local = idx & 262143;
            K = 512; in_ld = 512;
            src = (which == 0) ? p.W1b : (which == 1) ? p.W1c : (which == 2) ? p.W2b : p.W2c;
            dst = WP + (long)which * 524288;
            o = local >> 9; k = local & 511;
        } else {
            int local = idx - 1048576;
            K = 1024; in_ld = 1536; src = p.W2a; dst = WP2a;
            o = local >> 10; k = local & 1023;
        }
        float v = src[(long)o * in_ld + k];
        unsigned short hi = f2bf(v);
        dst[(long)o * 2 * K + k] = hi;
        dst[(long)o * 2 * K + K + k] = f2bf(v - bf2f(hi));
    }
    for (int l = blockIdx.x * 256 + t; l < ZERO_WORDS; l += stride) zb[l] = 0.f;
    const int lane = t & 63;
    for (int gid = blockIdx.x * 4 + (t >> 6); gid < 1024; gid += gridDim.x * 4) {
        int b = gid >> 9, o = gid & 511;
        float acc = 0.f;
        const float* wr = p.W1a + (long)o * 514;
        const float* zv = p.z + b * 512;
        for (int k = lane; k < 512; k += 64) acc += wr[k] * zv[k];
        #pragma unroll
        for (int off = 32; off > 0; off >>= 1) acc += __shfl_down(acc, off, 64);
        if (lane == 0) c1[gid] = acc + p.b1a[o];
    }
}

// ================= layer 1a: rank-2 pointwise, emit packed [Xh|Xl] =================
__global__ void g_layer_a(Params p) {
    unsigned short* X1P = (unsigned short*)(p.wsb + OFF_X1P);
    const float* c1 = (const float*)(p.wsb + OFF_C1);
    const int stride = gridDim.x * 256;
    for (int idx = blockIdx.x * 256 + threadIdx.x; idx < 3145728; idx += stride) {
        int o = idx & 511;
        int r = idx >> 9;
        int b, n, side;
        if (r < 2048) { b = r >> 10; n = r & 1023; side = 32; }
        else          { int r2 = r - 2048; b = r2 >> 11; n = r2 & 2047; side = 46; }
        int row = n / side, col = n % side;
        double inv = 1.0 / (double)(side - 1);
        float lx = (row == side - 1) ? 1.0f : (float)(row * inv);
        float ly = (col == side - 1) ? 1.0f : (float)(col * inv);
        float h = c1[b * 512 + o] + p.W1a[(long)o * 514 + 512] * lx
                                  + p.W1a[(long)o * 514 + 513] * ly;
        h = (h > 0.f) ? h : SLOPE * h;
        unsigned short hi = f2bf(h);
        X1P[(long)r * 1024 + o] = hi;
        X1P[(long)r * 1024 + 512 + o] = f2bf(h - bf2f(hi));
    }
}

// ============ one GEMM tile: 64(o) x 32J(n), TERMS=3 split-bf16 / TERMS=1 bf16 ============
template<int TERMS, int J>
static __device__ void dev_gemm_tile(char* sm, int t, int tile,
    const unsigned short* __restrict__ Wp, int ldw,
    const unsigned short* __restrict__ Xp, int ldx, int K,
    const float* __restrict__ bias, bool biasPerB,
    unsigned short* __restrict__ Xn, int ldxn, int lo_off, int row_off, int pack_min,
    const float* __restrict__ Wx, float* __restrict__ hacc,
    unsigned* __restrict__ globE) {

    constexpr int NT = 32 * J;
    constexpr int NSA = (TERMS == 3) ? 4 : 2;
    constexpr int NSB = (TERMS == 3) ? (2 * J) : J;
    constexpr int NSLOT = NSA + NSB;

    const int nb0 = (tile & 63) * NT;
    const int ob0 = (tile >> 6) * 64;

    const unsigned short* gp[NSLOT];
    int lo_[NSLOT];
    #pragma unroll
    for (int s = 0; s < NSA; ++s) {
        int half = s >> 1, part = s & 1;
        int j2 = (part << 8) + t;
        int r = j2 >> 3, cl = j2 & 7, cs = cl ^ (r & 7);
        gp[s] = Wp + (long)(ob0 + r) * ldw + half * K + cs * 8;
        lo_[s] = half * 8192 + j2 * 16;
    }
    #pragma unroll
    for (int s = 0; s < NSB; ++s) {
        int half = (TERMS == 3) ? (s / J) : 0;
        int part = (TERMS == 3) ? (s % J) : s;
        int j2 = (part << 8) + t;
        int r = j2 >> 3, cl = j2 & 7, cs = cl ^ (r & 7);
        gp[NSA + s] = Xp + (long)(nb0 + r) * ldx + half * K + cs * 8;
        lo_[NSA + s] = 16384 + half * (4096 * J) + j2 * 16;
    }

    const int lane = t & 63, w = t >> 6;
    const int wy = w >> 1, wx = w & 1;
    const int quad = lane >> 4, l15 = lane & 15;
    const int rowA = (wy * 32 + l15) * 128;
    const int ca0 = (quad ^ (l15 & 7)) * 16;
    const int ca1 = ((quad + 4) ^ (l15 & 7)) * 16;

    f32x4 acc[2][J];
    #pragma unroll
    for (int i = 0; i < 2; ++i)
        #pragma unroll
        for (int j = 0; j < J; ++j) { f32x4 zz = {0.f, 0.f, 0.f, 0.f}; acc[i][j] = zz; }

    for (int k0 = 0; k0 < K; k0 += 64) {
        #pragma unroll
        for (int s = 0; s < NSLOT; ++s)
            __builtin_amdgcn_global_load_lds(
                (const __attribute__((address_space(1))) void*)(const void*)(gp[s] + k0),
                (__attribute__((address_space(3))) void*)(void*)(sm + lo_[s]),
                16, 0, 0);
        __syncthreads();
        #pragma unroll
        for (int sub = 0; sub < 2; ++sub) {
            const int cb = (sub == 0) ? ca0 : ca1;
            bf16x8 ah[2], bh[J];
            #pragma unroll
            for (int i = 0; i < 2; ++i)
                ah[i] = *(const bf16x8*)(const void*)(sm + rowA + i * 2048 + cb);
            #pragma unroll
            for (int j = 0; j < J; ++j)
                bh[j] = *(const bf16x8*)(const void*)(sm + 16384 + (wx * 16 * J + j * 16 + l15) * 128 + cb);
            if (TERMS == 3) {
                bf16x8 al[2], bl[J];
                #pragma unroll
                for (int i = 0; i < 2; ++i)
                    al[i] = *(const bf16x8*)(const void*)(sm + 8192 + rowA + i * 2048 + cb);
                #pragma unroll
                for (int j = 0; j < J; ++j)
                    bl[j] = *(const bf16x8*)(const void*)(sm + 16384 + 4096 * J + (wx * 16 * J + j * 16 + l15) * 128 + cb);
                #pragma unroll
                for (int i = 0; i < 2; ++i)
                    #pragma unroll
                    for (int j = 0; j < J; ++j) {
                        acc[i][j] = __builtin_amdgcn_mfma_f32_16x16x32_bf16(ah[i], bh[j], acc[i][j], 0, 0, 0);
                        acc[i][j] = __builtin_amdgcn_mfma_f32_16x16x32_bf16(ah[i], bl[j], acc[i][j], 0, 0, 0);
                        acc[i][j] = __builtin_amdgcn_mfma_f32_16x16x32_bf16(al[i], bh[j], acc[i][j], 0, 0, 0);
                    }
            } else {
                #pragma unroll
                for (int i = 0; i < 2; ++i)
                    #pragma unroll
                    for (int j = 0; j < J; ++j)
                        acc[i][j] = __builtin_amdgcn_mfma_f32_16x16x32_bf16(ah[i], bh[j], acc[i][j], 0, 0, 0);
            }
        }
        __syncthreads();
    }

    // epilogue
    float val[2][J][4];
    #pragma unroll
    for (int j = 0; j < J; ++j) {
        int n = nb0 + wx * 16 * J + j * 16 + l15;
        int bofs = biasPerB ? ((n >> 11) * 512) : 0;
        #pragma unroll
        for (int i = 0; i < 2; ++i) {
            int ob = ob0 + wy * 32 + i * 16 + quad * 4;
            #pragma unroll
            for (int r = 0; r < 4; ++r) {
                float x = acc[i][j][r] + bias[bofs + ob + r];
                val[i][j][r] = (x > 0.f) ? x : SLOPE * x;
            }
        }
        if (Xn && n >= pack_min) {
            long nl = n - row_off;
            #pragma unroll
            for (int i = 0; i < 2; ++i) {
                int ob = ob0 + wy * 32 + i * 16 + quad * 4;
                u16x4 h4;
                #pragma unroll
                for (int r = 0; r < 4; ++r) h4[r] = f2bf(val[i][j][r]);
                *(u16x4*)(void*)(Xn + nl * ldxn + ob) = h4;
                if (lo_off) {
                    u16x4 l4;
                    #pragma unroll
                    for (int r = 0; r < 4; ++r) l4[r] = f2bf(val[i][j][r] - bf2f(h4[r]));
                    *(u16x4*)(void*)(Xn + nl * ldxn + lo_off + ob) = l4;
                }
            }
        }
    }

    if (hacc) {
        __syncthreads();
        float* smh = (float*)sm;                 // [NT][4]
        unsigned* smg = (unsigned*)(sm + 2048);  // [2][64]
        for (int l = t; l < NT * 4; l += 256) smh[l] = 0.f;
        if (t < 128) smg[t] = 0u;
        __syncthreads();
        float wxv[3][2][4];
        #pragma unroll
        for (int ch = 0; ch < 3; ++ch)
            #pragma unroll
            for (int i = 0; i < 2; ++i)
                #pragma unroll
                for (int r = 0; r < 4; ++r)
                    wxv[ch][i][r] = Wx[ch * 512 + ob0 + wy * 32 + i * 16 + quad * 4 + r];
        #pragma unroll
        for (int j = 0; j < J; ++j) {
            int nl = wx * 16 * J + j * 16 + l15;
            int n = nb0 + nl;
            float p0 = 0.f, p1 = 0.f, p2 = 0.f;
            #pragma unroll
            for (int i = 0; i < 2; ++i)
                #pragma unroll
                for (int r = 0; r < 4; ++r) {
                    float v = val[i][j][r];
                    p0 += v * wxv[0][i][r];
                    p1 += v * wxv[1][i][r];
                    p2 += v * wxv[2][i][r];
                }
            atomicAdd(&smh[nl * 4 + 0], p0);
            atomicAdd(&smh[nl * 4 + 1], p1);
            atomicAdd(&smh[nl * 4 + 2], p2);
            if (globE && n >= 2048) {
                int bsel = (n >= 4096) ? 1 : 0;
                #pragma unroll
                for (int i = 0; i < 2; ++i)
                    #pragma unroll
                    for (int r = 0; r < 4; ++r)
                        atomicMax(&smg[bsel * 64 + wy * 32 + i * 16 + quad * 4 + r],
                                  fenc(val[i][j][r]));
            }
        }
        __syncthreads();
        if (t < NT) {
            atomicAdd(&hacc[(long)(nb0 + t) * 4 + 0], smh[t * 4 + 0]);
            atomicAdd(&hacc[(long)(nb0 + t) * 4 + 1], smh[t * 4 + 1]);
            atomicAdd(&hacc[(long)(nb0 + t) * 4 + 2], smh[t * 4 + 2]);
        }
        if (globE && t < 128)
            atomicMax(&globE[(t >> 6) * 512 + ob0 + (t & 63)], smg[t]);
        __syncthreads();
    }
}

// ================= GEMM arg macros =================
#define WPB(wsb)  ((unsigned short*)((wsb) + OFF_WP))
#define GEMM1B_ARGS(p) WPB(p.wsb), 1024, (unsigned short*)(p.wsb + OFF_X1P), 1024, 512, p.b1b, false, \
                       (unsigned short*)(p.wsb + OFF_XMP), 1024, 512, 0, 0, nullptr, nullptr, nullptr
#define GEMM1C_ARGS(p) WPB(p.wsb) + 524288, 1024, (unsigned short*)(p.wsb + OFF_XMP), 1024, 512, p.b1c, false, \
                       (unsigned short*)(p.wsb + OFF_X2P), 1024, 0, 2048, 2048, p.Wx1, \
                       (float*)(p.wsb + OFF_HACC1), (unsigned*)(p.wsb + OFF_GLOBE)
#define GEMM2A_ARGS(p) WPB(p.wsb) + 2097152, 2048, (unsigned short*)(p.wsb + OFF_X2P), 1024, 1024, \
                       (const float*)(p.wsb + OFF_GBIAS), true, \
                       (unsigned short*)(p.wsb + OFF_X3P), 512, 0, 0, 0, nullptr, nullptr, nullptr
#define GEMM2B_ARGS(p) WPB(p.wsb) + 1048576, 1024, (unsigned short*)(p.wsb + OFF_X3P), 512, 512, p.b2b, false, \
                       (unsigned short*)(p.wsb + OFF_X4P), 512, 0, 0, 0, nullptr, nullptr, nullptr
#define GEMM2C_ARGS(p) WPB(p.wsb) + 1572864, 1024, (unsigned short*)(p.wsb + OFF_X4P), 512, 512, p.b2c, false, \
                       (unsigned short*)nullptr, 0, 0, 0, 0, p.Wx2, (float*)(p.wsb + OFF_HACC2), (unsigned*)nullptr

__global__ __launch_bounds__(256, 2) void g_gemm1b(Params p) {
    __shared__ __align__(16) char sm[40960];
    for (int tile = blockIdx.x; tile < 512; tile += gridDim.x)
        dev_gemm_tile<3, 3>(sm, threadIdx.x, tile, GEMM1B_ARGS(p));
}
__global__ __launch_bounds__(256, 2) void g_gemm1c(Params p) {
    __shared__ __align__(16) char sm[40960];
    for (int tile = blockIdx.x; tile < 512; tile += gridDim.x)
        dev_gemm_tile<3, 3>(sm, threadIdx.x, tile, GEMM1C_ARGS(p));
}
__global__ __launch_bounds__(256, 2) void g_gemm2a(Params p) {
    __shared__ __align__(16) char sm[40960];
    for (int tile = blockIdx.x; tile < 512; tile += gridDim.x)
        dev_gemm_tile<1, 2>(sm, threadIdx.x, tile, GEMM2A_ARGS(p));
}
__global__ __launch_bounds__(256, 2) void g_gemm2b(Params p) {
    __shared__ __align__(16) char sm[40960];
    for (int tile = blockIdx.x; tile < 512; tile += gridDim.x)
        dev_gemm_tile<1, 2>(sm, threadIdx.x, tile, GEMM2B_ARGS(p));
}
// gemm2c + last-block fin2 (atomic ticket; completion count, not a barrier)
__global__ __launch_bounds__(256, 2) void g_gemm2c(Params p) {
    __shared__ __align__(16) char sm[40960];
    for (int tile = blockIdx.x; tile < 512; tile += gridDim.x)
        dev_gemm_tile<1, 2>(sm, threadIdx.x, tile, GEMM2C_ARGS(p));
    __threadfence();
    __shared__ int ticket;
    if (threadIdx.x == 0) ticket = atomicAdd((int*)(p.wsb + OFF_CNT), 1);
    __syncthreads();
    if (ticket == (int)gridDim.x - 1) {
        __threadfence();
        const float* hacc2 = (const float*)(p.wsb + OFF_HACC2);
        for (int r = threadIdx.x; r < 4096; r += 256) {
            #pragma unroll
            for (int ch = 0; ch < 3; ++ch) {
                float a = hacc2[(long)r * 4 + ch] + p.bx2[ch];
                p.out1[(long)r * 3 + ch] = p.out2[(long)r * 3 + ch]
                                         + 0.1f * (1.f / (1.f + expf(-a)) - 0.5f);
            }
        }
    }
}

// ===== ball query + gather-max; side-work: stage-1 heads (blocks 0..23), gbias (24..279) =====
__global__ __launch_bounds__(256) void g_ball(Params p) {
    __shared__ float fxs[2048], fys[2048], fzs[2048];
    __shared__ int idxl[64];
    __shared__ int wcnt[4];
    __shared__ float part[8][256];
    const int bx = blockIdx.x, t = threadIdx.x;
    const int i = bx & 2047, b = bx >> 11;
    const int lane = t & 63, wv = t >> 6;
    const float* hacc1 = (const float*)(p.wsb + OFF_HACC1);
    unsigned short* X2P = (unsigned short*)(p.wsb + OFF_X2P);

    if (bx < 24) {   // stage-1 sigmoid heads -> out0 / out2
        int r = bx * 256 + t;
        float* dst = (r < 2048) ? (p.out0 + (long)r * 3) : (p.out2 + (long)(r - 2048) * 3);
        #pragma unroll
        for (int ch = 0; ch < 3; ++ch) {
            float a = hacc1[(long)r * 4 + ch] + p.bx1[ch];
            dst[ch] = 1.f / (1.f + expf(-a)) - 0.5f;
        }
    } else if (bx < 280) {   // gbias GEMV from globE
        const unsigned* globE = (const unsigned*)(p.wsb + OFF_GLOBE);
        float* gbias = (float*)(p.wsb + OFF_GBIAS);
        int gid = (bx - 24) * 4 + wv;   // 0..1023
        int bb = gid >> 9, o = gid & 511;
        float acc = 0.f;
        const float* wr = p.W2a + (long)o * 1536 + 1024;
        for (int k = lane; k < 512; k += 64) acc += wr[k] * fdec(globE[bb * 512 + k]);
        #pragma unroll
        for (int off = 32; off > 0; off >>= 1) acc += __shfl_down(acc, off, 64);
        if (lane == 0) gbias[gid] = acc + p.b2a[o];
    }

    // fine points of batch b from hacc1 (bit-identical to out2 formula) -> LDS
    const float* hrow = hacc1 + (long)(2048 + b * 2048) * 4;
    for (int j = t; j < 2048; j += 256) {
        f32x4 a = *(const f32x4*)(const void*)(hrow + (long)j * 4);
        fxs[j] = 1.f / (1.f + expf(-(a[0] + p.bx1[0]))) - 0.5f;
        fys[j] = 1.f / (1.f + expf(-(a[1] + p.bx1[1]))) - 0.5f;
        fzs[j] = 1.f / (1.f + expf(-(a[2] + p.bx1[2]))) - 0.5f;
    }
    __syncthreads();

    float xi = fxs[i], yi = fys[i], zi = fzs[i];
    float sqi = __fadd_rn(__fadd_rn(__fmul_rn(xi, xi), __fmul_rn(yi, yi)), __fmul_rn(zi, zi));
    int cnt = 0;
    for (int it = 0; it < 8; ++it) {
        int j = it * 256 + t;
        float xj = fxs[j], yj = fys[j], zj = fzs[j];
        float sqj = __fadd_rn(__fadd_rn(__fmul_rn(xj, xj), __fmul_rn(yj, yj)), __fmul_rn(zj, zj));
        float dot = __fadd_rn(__fadd_rn(__fmul_rn(xi, xj), __fmul_rn(yi, yj)), __fmul_rn(zi, zj));
        float d2 = __fsub_rn(__fadd_rn(sqi, sqj), __fmul_rn(2.0f, dot));
        bool pred = d2 < 0.01f;
        unsigned long long m = __ballot(pred);
        if (lane == 0) wcnt[wv] = __popcll(m);
        __syncthreads();
        int wbase = cnt;
        #pragma unroll
        for (int q = 0; q < 3; ++q) { if (q < wv) wbase += wcnt[q]; }
        int total = wcnt[0] + wcnt[1] + wcnt[2] + wcnt[3];
        int rank = wbase + __popcll(m & ((1ull << lane) - 1ull));
        if (pred && rank < 64) idxl[rank] = j;
        cnt += total;
        if (cnt >= 64) break;       // uniform across block
        __syncthreads();
    }
    __syncthreads();
    int m = min(cnt, 64);

    const unsigned short* hb = X2P + (long)b * 2048 * 1024;
    int g = t & 63, q = t >> 6;
    float mx[8];
    #pragma unroll
    for (int r = 0; r < 8; ++r) mx[r] = -1e30f;
    for (int jj = q; jj < m; jj += 4) {
        u16x8 v = *(const u16x8*)(const void*)(hb + (long)idxl[jj] * 1024 + g * 8);
        #pragma unroll
        for (int r = 0; r < 8; ++r) mx[r] = fmaxf(mx[r], bf2f(v[r]));
    }
    #pragma unroll
    for (int r = 0; r < 8; ++r) part[r][t] = mx[r];
    __syncthreads();
    if (t < 64) {
        unsigned short* orow = X2P + (long)(b * 2048 + i) * 1024;
        u16x8 hi;
        #pragma unroll
        for (int r = 0; r < 8; ++r) {
            float v0 = fmaxf(fmaxf(part[r][t], part[r][t + 64]),
                             fmaxf(part[r][t + 128], part[r][t + 192]));
            hi[r] = (unsigned short)(__float_as_uint(v0) >> 16);   // exact: bf16-valued
        }
        *(u16x8*)(void*)(orow + 512 + t * 8) = hi;
    }
}

// ================= launch =================
extern "C" void kernel_launch(void* const* d_in, const int* in_sizes, int n_in,
                              void* d_out, int out_size, void* d_ws, size_t ws_size,
                              hipStream_t stream) {
    Params p;
    p.z   = (const float*)d_in[0];
    p.W1a = (const float*)d_in[1];
    p.b1a = (const float*)d_in[2];
    p.W1b = (const float*)d_in[3];
    p.b1b = (const float*)d_in[4];
    p.W1c = (const float*)d_in[5];
    p.b1c = (const float*)d_in[6];
    p.Wx1 = (const float*)d_in[7];
    p.bx1 = (const float*)d_in[8];
    p.W2a = (const float*)d_in[9];
    p.b2a = (const float*)d_in[10];
    p.W2b = (const float*)d_in[11];
    p.b2b = (const float*)d_in[12];
    p.W2c = (const float*)d_in[13];
    p.b2c = (const float*)d_in[14];
    p.Wx2 = (const float*)d_in[15];
    p.bx2 = (const float*)d_in[16];
    p.wsb = (char*)d_ws;
    p.out0 = (float*)d_out;              // (2,1024,3)
    p.out1 = p.out0 + 2 * 1024 * 3;      // (2,2048,3)
    p.out2 = p.out1 + 2 * 2048 * 3;      // (2,2048,3) fine_points

    g_prep<<<2048, 256, 0, stream>>>(p);
    g_layer_a<<<2048, 256, 0, stream>>>(p);
    g_gemm1b<<<512, 256, 0, stream>>>(p);
    g_gemm1c<<<512, 256, 0, stream>>>(p);
    g_ball<<<4096, 256, 0, stream>>>(p);
    g_gemm2a<<<512, 256, 0, stream>>>(p);
    g_gemm2b<<<512, 256, 0, stream>>>(p);
    g_gemm2c<<<512, 256, 0, stream>>>(p);
}

// Round 9
// 215.519 us; speedup vs baseline: 2.5772x; 1.2027x over previous
//
#include <hip/hip_runtime.h>
#include <math.h>

#define SLOPE 0.2f

typedef short bf16x8 __attribute__((ext_vector_type(8)));
typedef float f32x4 __attribute__((ext_vector_type(4)));
typedef unsigned short u16x4 __attribute__((ext_vector_type(4)));
typedef unsigned short u16x8 __attribute__((ext_vector_type(8)));

static __device__ __forceinline__ unsigned short f2bf(float x) {
    unsigned int u = __float_as_uint(x);
    unsigned int r = (u + 0x7fffu + ((u >> 16) & 1u)) >> 16;   // RNE
    return (unsigned short)r;
}
static __device__ __forceinline__ float bf2f(unsigned short h) {
    return __uint_as_float(((unsigned int)h) << 16);
}
static __device__ __forceinline__ unsigned fenc(float f) {
    unsigned u = __float_as_uint(f);
    return (u & 0x80000000u) ? ~u : (u | 0x80000000u);
}
static __device__ __forceinline__ float fdec(unsigned u) {
    unsigned b = (u & 0x80000000u) ? (u & 0x7FFFFFFFu) : ~u;
    return __uint_as_float(b);
}

// ---- ws byte offsets ----
#define OFF_WP     0
#define OFF_X1P    6291456
#define OFF_XMP    18874368
#define OFF_X2P    31457280
#define OFF_X3P    39845888
#define OFF_X4P    44040192
#define OFF_GLOBE  48238592
#define OFF_GBIAS  48242688
#define OFF_HACC1  48246784   // [6144][4] f32
#define OFF_HACC2  48345088   // [4096][4] f32
#define ZERO_WORDS 42496      // globE..hacc2 end, in f32 words

struct Params {
    const float *z, *W1a, *b1a, *W1b, *b1b, *W1c, *b1c, *Wx1, *bx1;
    const float *W2a, *b2a, *W2b, *b2b, *W2c, *b2c, *Wx2, *bx2;
    char* wsb;
    float *out0, *out1, *out2;
};

// ====== prep: pack weights + zero accumulators + fused c1-GEMV/layer-1a ======
// layer-a tasks: 192 blocks, task = (kc in 0..1) x (nc in 0..95, 64 rows each).
// Each block recomputes the c1 slice it needs (256 k x 512 j GEMV) - trivial redundancy,
// removes the separate c1 kernel and the cross-kernel dependency.
__global__ void g_prep(Params p) {
    __shared__ float zsh[512];
    unsigned short* WP   = (unsigned short*)(p.wsb + OFF_WP);
    unsigned short* WP2a = WP + 2097152;
    unsigned short* X1P  = (unsigned short*)(p.wsb + OFF_X1P);
    float* zb = (float*)(p.wsb + OFF_GLOBE);
    const int t = threadIdx.x;
    const int stride = gridDim.x * 256;
    for (int idx = blockIdx.x * 256 + t; idx < 1572864; idx += stride) {
        const float* src; unsigned short* dst; int o, k, K, in_ld;
        if (idx < 1048576) {
            int which = idx >> 18; int local = idx & 262143;
            K = 512; in_ld = 512;
            src = (which == 0) ? p.W1b : (which == 1) ? p.W1c : (which == 2) ? p.W2b : p.W2c;
            dst = WP + (long)which * 524288;
            o = local >> 9; k = local & 511;
        } else {
            int local = idx - 1048576;
            K = 1024; in_ld = 1536; src = p.W2a; dst = WP2a;
            o = local >> 10; k = local & 1023;
        }
        float v = src[(long)o * in_ld + k];
        unsigned short hi = f2bf(v);
        dst[(long)o * 2 * K + k] = hi;
        dst[(long)o * 2 * K + K + k] = f2bf(v - bf2f(hi));
    }
    for (int l = blockIdx.x * 256 + t; l < ZERO_WORDS; l += stride) zb[l] = 0.f;

    if (blockIdx.x < 192) {
        int task = blockIdx.x;
        int kc = task & 1;       // k-half
        int nc = task >> 1;      // 0..95, 64 rows each
        int r0 = nc * 64;
        int b, side, nbase;
        if (r0 < 1024)      { b = 0; side = 32; nbase = 0; }
        else if (r0 < 2048) { b = 1; side = 32; nbase = 1024; }
        else if (r0 < 4096) { b = 0; side = 46; nbase = 2048; }
        else                { b = 1; side = 46; nbase = 4096; }
        for (int j = t; j < 512; j += 256) zsh[j] = p.z[b * 512 + j];
        __syncthreads();
        int k = kc * 256 + t;
        const float* wr = p.W1a + (long)k * 514;
        float acc = p.b1a[k];
        for (int j = 0; j < 512; ++j) acc += wr[j] * zsh[j];
        float w512 = wr[512], w513 = wr[513];
        double inv = 1.0 / (double)(side - 1);
        int nl0 = r0 - nbase;
        int row = nl0 / side, col = nl0 % side;
        for (int rr = 0; rr < 64; ++rr) {
            float lx = (row == side - 1) ? 1.0f : (float)(row * inv);
            float ly = (col == side - 1) ? 1.0f : (float)(col * inv);
            float h = acc + w512 * lx + w513 * ly;
            h = (h > 0.f) ? h : SLOPE * h;
            unsigned short hi = f2bf(h);
            long r = r0 + rr;
            X1P[r * 1024 + k] = hi;
            X1P[r * 1024 + 512 + k] = f2bf(h - bf2f(hi));
            if (++col == side) { col = 0; ++row; }
        }
    }
}

// ============ one GEMM tile: 64(o) x 32J(n), TERMS=3 split-bf16 / TERMS=1 bf16 ============
template<int TERMS, int J>
static __device__ void dev_gemm_tile(char* sm, int t, int tile,
    const unsigned short* __restrict__ Wp, int ldw,
    const unsigned short* __restrict__ Xp, int ldx, int K,
    const float* __restrict__ bias, bool biasPerB,
    unsigned short* __restrict__ Xn, int ldxn, int lo_off, int row_off, int pack_min,
    const float* __restrict__ Wx, float* __restrict__ hacc,
    unsigned* __restrict__ globE) {

    constexpr int NT = 32 * J;
    constexpr int NSA = (TERMS == 3) ? 4 : 2;
    constexpr int NSB = (TERMS == 3) ? (2 * J) : J;
    constexpr int NSLOT = NSA + NSB;

    const int nb0 = (tile & 63) * NT;
    const int ob0 = (tile >> 6) * 64;

    const unsigned short* gp[NSLOT];
    int lo_[NSLOT];
    #pragma unroll
    for (int s = 0; s < NSA; ++s) {
        int half = s >> 1, part = s & 1;
        int j2 = (part << 8) + t;
        int r = j2 >> 3, cl = j2 & 7, cs = cl ^ (r & 7);
        gp[s] = Wp + (long)(ob0 + r) * ldw + half * K + cs * 8;
        lo_[s] = half * 8192 + j2 * 16;
    }
    #pragma unroll
    for (int s = 0; s < NSB; ++s) {
        int half = (TERMS == 3) ? (s / J) : 0;
        int part = (TERMS == 3) ? (s % J) : s;
        int j2 = (part << 8) + t;
        int r = j2 >> 3, cl = j2 & 7, cs = cl ^ (r & 7);
        gp[NSA + s] = Xp + (long)(nb0 + r) * ldx + half * K + cs * 8;
        lo_[NSA + s] = 16384 + half * (4096 * J) + j2 * 16;
    }

    const int lane = t & 63, w = t >> 6;
    const int wy = w >> 1, wx = w & 1;
    const int quad = lane >> 4, l15 = lane & 15;
    const int rowA = (wy * 32 + l15) * 128;
    const int ca0 = (quad ^ (l15 & 7)) * 16;
    const int ca1 = ((quad + 4) ^ (l15 & 7)) * 16;

    f32x4 acc[2][J];
    #pragma unroll
    for (int i = 0; i < 2; ++i)
        #pragma unroll
        for (int j = 0; j < J; ++j) { f32x4 zz = {0.f, 0.f, 0.f, 0.f}; acc[i][j] = zz; }

    for (int k0 = 0; k0 < K; k0 += 64) {
        #pragma unroll
        for (int s = 0; s < NSLOT; ++s)
            __builtin_amdgcn_global_load_lds(
                (const __attribute__((address_space(1))) void*)(const void*)(gp[s] + k0),
                (__attribute__((address_space(3))) void*)(void*)(sm + lo_[s]),
                16, 0, 0);
        __syncthreads();
        #pragma unroll
        for (int sub = 0; sub < 2; ++sub) {
            const int cb = (sub == 0) ? ca0 : ca1;
            bf16x8 ah[2], bh[J];
            #pragma unroll
            for (int i = 0; i < 2; ++i)
                ah[i] = *(const bf16x8*)(const void*)(sm + rowA + i * 2048 + cb);
            #pragma unroll
            for (int j = 0; j < J; ++j)
                bh[j] = *(const bf16x8*)(const void*)(sm + 16384 + (wx * 16 * J + j * 16 + l15) * 128 + cb);
            if (TERMS == 3) {
                bf16x8 al[2], bl[J];
                #pragma unroll
                for (int i = 0; i < 2; ++i)
                    al[i] = *(const bf16x8*)(const void*)(sm + 8192 + rowA + i * 2048 + cb);
                #pragma unroll
                for (int j = 0; j < J; ++j)
                    bl[j] = *(const bf16x8*)(const void*)(sm + 16384 + 4096 * J + (wx * 16 * J + j * 16 + l15) * 128 + cb);
                #pragma unroll
                for (int i = 0; i < 2; ++i)
                    #pragma unroll
                    for (int j = 0; j < J; ++j) {
                        acc[i][j] = __builtin_amdgcn_mfma_f32_16x16x32_bf16(ah[i], bh[j], acc[i][j], 0, 0, 0);
                        acc[i][j] = __builtin_amdgcn_mfma_f32_16x16x32_bf16(ah[i], bl[j], acc[i][j], 0, 0, 0);
                        acc[i][j] = __builtin_amdgcn_mfma_f32_16x16x32_bf16(al[i], bh[j], acc[i][j], 0, 0, 0);
                    }
            } else {
                #pragma unroll
                for (int i = 0; i < 2; ++i)
                    #pragma unroll
                    for (int j = 0; j < J; ++j)
                        acc[i][j] = __builtin_amdgcn_mfma_f32_16x16x32_bf16(ah[i], bh[j], acc[i][j], 0, 0, 0);
            }
        }
        __syncthreads();
    }

    // epilogue
    float val[2][J][4];
    #pragma unroll
    for (int j = 0; j < J; ++j) {
        int n = nb0 + wx * 16 * J + j * 16 + l15;
        int bofs = biasPerB ? ((n >> 11) * 512) : 0;
        #pragma unroll
        for (int i = 0; i < 2; ++i) {
            int ob = ob0 + wy * 32 + i * 16 + quad * 4;
            #pragma unroll
            for (int r = 0; r < 4; ++r) {
                float x = acc[i][j][r] + bias[bofs + ob + r];
                val[i][j][r] = (x > 0.f) ? x : SLOPE * x;
            }
        }
        if (Xn && n >= pack_min) {
            long nl = n - row_off;
            #pragma unroll
            for (int i = 0; i < 2; ++i) {
                int ob = ob0 + wy * 32 + i * 16 + quad * 4;
                u16x4 h4;
                #pragma unroll
                for (int r = 0; r < 4; ++r) h4[r] = f2bf(val[i][j][r]);
                *(u16x4*)(void*)(Xn + nl * ldxn + ob) = h4;
                if (lo_off) {
                    u16x4 l4;
                    #pragma unroll
                    for (int r = 0; r < 4; ++r) l4[r] = f2bf(val[i][j][r] - bf2f(h4[r]));
                    *(u16x4*)(void*)(Xn + nl * ldxn + lo_off + ob) = l4;
                }
            }
        }
    }

    if (hacc) {
        __syncthreads();
        float* smh = (float*)sm;                 // [NT][4]
        unsigned* smg = (unsigned*)(sm + 2048);  // [2][64]
        for (int l = t; l < NT * 4; l += 256) smh[l] = 0.f;
        if (t < 128) smg[t] = 0u;
        __syncthreads();
        float wxv[3][2][4];
        #pragma unroll
        for (int ch = 0; ch < 3; ++ch)
            #pragma unroll
            for (int i = 0; i < 2; ++i)
                #pragma unroll
                for (int r = 0; r < 4; ++r)
                    wxv[ch][i][r] = Wx[ch * 512 + ob0 + wy * 32 + i * 16 + quad * 4 + r];
        #pragma unroll
        for (int j = 0; j < J; ++j) {
            int nl = wx * 16 * J + j * 16 + l15;
            int n = nb0 + nl;
            float p0 = 0.f, p1 = 0.f, p2 = 0.f;
            #pragma unroll
            for (int i = 0; i < 2; ++i)
                #pragma unroll
                for (int r = 0; r < 4; ++r) {
                    float v = val[i][j][r];
                    p0 += v * wxv[0][i][r];
                    p1 += v * wxv[1][i][r];
                    p2 += v * wxv[2][i][r];
                }
            atomicAdd(&smh[nl * 4 + 0], p0);
            atomicAdd(&smh[nl * 4 + 1], p1);
            atomicAdd(&smh[nl * 4 + 2], p2);
            if (globE && n >= 2048) {
                int bsel = (n >= 4096) ? 1 : 0;
                #pragma unroll
                for (int i = 0; i < 2; ++i)
                    #pragma unroll
                    for (int r = 0; r < 4; ++r)
                        atomicMax(&smg[bsel * 64 + wy * 32 + i * 16 + quad * 4 + r],
                                  fenc(val[i][j][r]));
            }
        }
        __syncthreads();
        if (t < NT) {
            atomicAdd(&hacc[(long)(nb0 + t) * 4 + 0], smh[t * 4 + 0]);
            atomicAdd(&hacc[(long)(nb0 + t) * 4 + 1], smh[t * 4 + 1]);
            atomicAdd(&hacc[(long)(nb0 + t) * 4 + 2], smh[t * 4 + 2]);
        }
        if (globE && t < 128)
            atomicMax(&globE[(t >> 6) * 512 + ob0 + (t & 63)], smg[t]);
        __syncthreads();
    }
}

// ================= GEMM arg macros =================
#define WPB(wsb)  ((unsigned short*)((wsb) + OFF_WP))
#define GEMM1B_ARGS(p) WPB(p.wsb), 1024, (unsigned short*)(p.wsb + OFF_X1P), 1024, 512, p.b1b, false, \
                       (unsigned short*)(p.wsb + OFF_XMP), 1024, 512, 0, 0, nullptr, nullptr, nullptr
#define GEMM1C_ARGS(p) WPB(p.wsb) + 524288, 1024, (unsigned short*)(p.wsb + OFF_XMP), 1024, 512, p.b1c, false, \
                       (unsigned short*)(p.wsb + OFF_X2P), 1024, 0, 2048, 2048, p.Wx1, \
                       (float*)(p.wsb + OFF_HACC1), (unsigned*)(p.wsb + OFF_GLOBE)
#define GEMM2A_ARGS(p) WPB(p.wsb) + 2097152, 2048, (unsigned short*)(p.wsb + OFF_X2P), 1024, 1024, \
                       (const float*)(p.wsb + OFF_GBIAS), true, \
                       (unsigned short*)(p.wsb + OFF_X3P), 512, 0, 0, 0, nullptr, nullptr, nullptr
#define GEMM2B_ARGS(p) WPB(p.wsb) + 1048576, 1024, (unsigned short*)(p.wsb + OFF_X3P), 512, 512, p.b2b, false, \
                       (unsigned short*)(p.wsb + OFF_X4P), 512, 0, 0, 0, nullptr, nullptr, nullptr
#define GEMM2C_ARGS(p) WPB(p.wsb) + 1572864, 1024, (unsigned short*)(p.wsb + OFF_X4P), 512, 512, p.b2c, false, \
                       (unsigned short*)nullptr, 0, 0, 0, 0, p.Wx2, (float*)(p.wsb + OFF_HACC2), (unsigned*)nullptr

__global__ __launch_bounds__(256, 2) void g_gemm1b(Params p) {
    __shared__ __align__(16) char sm[40960];
    for (int tile = blockIdx.x; tile < 512; tile += gridDim.x)
        dev_gemm_tile<3, 3>(sm, threadIdx.x, tile, GEMM1B_ARGS(p));
}
__global__ __launch_bounds__(256, 2) void g_gemm1c(Params p) {
    __shared__ __align__(16) char sm[40960];
    for (int tile = blockIdx.x; tile < 512; tile += gridDim.x)
        dev_gemm_tile<3, 3>(sm, threadIdx.x, tile, GEMM1C_ARGS(p));
}
__global__ __launch_bounds__(256, 2) void g_gemm2a(Params p) {
    __shared__ __align__(16) char sm[40960];
    for (int tile = blockIdx.x; tile < 512; tile += gridDim.x)
        dev_gemm_tile<1, 2>(sm, threadIdx.x, tile, GEMM2A_ARGS(p));
}
__global__ __launch_bounds__(256, 2) void g_gemm2b(Params p) {
    __shared__ __align__(16) char sm[40960];
    for (int tile = blockIdx.x; tile < 512; tile += gridDim.x)
        dev_gemm_tile<1, 2>(sm, threadIdx.x, tile, GEMM2B_ARGS(p));
}
__global__ __launch_bounds__(256, 2) void g_gemm2c(Params p) {
    __shared__ __align__(16) char sm[40960];
    for (int tile = blockIdx.x; tile < 512; tile += gridDim.x)
        dev_gemm_tile<1, 2>(sm, threadIdx.x, tile, GEMM2C_ARGS(p));
}

// ========== fin1: stage-1 sigmoid heads (blocks 0..23) + gbias GEMV (24..279) ==========
__global__ void g_fin1(Params p) {
    const float* hacc1 = (const float*)(p.wsb + OFF_HACC1);
    const int bx = blockIdx.x, t = threadIdx.x;
    if (bx < 24) {
        int r = bx * 256 + t;
        float* dst = (r < 2048) ? (p.out0 + (long)r * 3) : (p.out2 + (long)(r - 2048) * 3);
        #pragma unroll
        for (int ch = 0; ch < 3; ++ch) {
            float a = hacc1[(long)r * 4 + ch] + p.bx1[ch];
            dst[ch] = 1.f / (1.f + expf(-a)) - 0.5f;
        }
    } else {
        const unsigned* globE = (const unsigned*)(p.wsb + OFF_GLOBE);
        float* gbias = (float*)(p.wsb + OFF_GBIAS);
        const int lane = t & 63;
        int gid = (bx - 24) * 4 + (t >> 6);   // 0..1023
        int bb = gid >> 9, o = gid & 511;
        float acc = 0.f;
        const float* wr = p.W2a + (long)o * 1536 + 1024;
        for (int k = lane; k < 512; k += 64) acc += wr[k] * fdec(globE[bb * 512 + k]);
        #pragma unroll
        for (int off = 32; off > 0; off >>= 1) acc += __shfl_down(acc, off, 64);
        if (lane == 0) gbias[gid] = acc + p.b2a[o];
    }
}

// ===== ball query (parallel compaction) + bf16 gather-max (R5-style, small LDS) =====
__global__ __launch_bounds__(256) void g_ball(Params p) {
    __shared__ int idxl[64];
    __shared__ int wcnt[4];
    __shared__ float part[8][256];
    const int i = blockIdx.x, b = blockIdx.y;
    const int t = threadIdx.x, lane = t & 63, wv = t >> 6;
    unsigned short* X2P = (unsigned short*)(p.wsb + OFF_X2P);
    const float* fb = p.out2 + (long)b * 2048 * 3;
    float xi = fb[i * 3 + 0], yi = fb[i * 3 + 1], zi = fb[i * 3 + 2];
    float sqi = __fadd_rn(__fadd_rn(__fmul_rn(xi, xi), __fmul_rn(yi, yi)), __fmul_rn(zi, zi));
    int cnt = 0;
    for (int it = 0; it < 8; ++it) {
        int j = it * 256 + t;
        float xj = fb[j * 3 + 0], yj = fb[j * 3 + 1], zj = fb[j * 3 + 2];
        float sqj = __fadd_rn(__fadd_rn(__fmul_rn(xj, xj), __fmul_rn(yj, yj)), __fmul_rn(zj, zj));
        float dot = __fadd_rn(__fadd_rn(__fmul_rn(xi, xj), __fmul_rn(yi, yj)), __fmul_rn(zi, zj));
        float d2 = __fsub_rn(__fadd_rn(sqi, sqj), __fmul_rn(2.0f, dot));
        bool pred = d2 < 0.01f;
        unsigned long long m = __ballot(pred);
        if (lane == 0) wcnt[wv] = __popcll(m);
        __syncthreads();
        int wbase = cnt;
        #pragma unroll
        for (int q = 0; q < 3; ++q) { if (q < wv) wbase += wcnt[q]; }
        int total = wcnt[0] + wcnt[1] + wcnt[2] + wcnt[3];
        int rank = wbase + __popcll(m & ((1ull << lane) - 1ull));
        if (pred && rank < 64) idxl[rank] = j;
        cnt += total;
        if (cnt >= 64) break;       // uniform across block
        __syncthreads();
    }
    __syncthreads();
    int m = min(cnt, 64);

    const unsigned short* hb = X2P + (long)b * 2048 * 1024;
    int g = t & 63, q = t >> 6;
    float mx[8];
    #pragma unroll
    for (int r = 0; r < 8; ++r) mx[r] = -1e30f;
    for (int jj = q; jj < m; jj += 4) {
        u16x8 v = *(const u16x8*)(const void*)(hb + (long)idxl[jj] * 1024 + g * 8);
        #pragma unroll
        for (int r = 0; r < 8; ++r) mx[r] = fmaxf(mx[r], bf2f(v[r]));
    }
    #pragma unroll
    for (int r = 0; r < 8; ++r) part[r][t] = mx[r];
    __syncthreads();
    if (t < 64) {
        unsigned short* orow = X2P + (long)(b * 2048 + i) * 1024;
        u16x8 hi;
        #pragma unroll
        for (int r = 0; r < 8; ++r) {
            float v0 = fmaxf(fmaxf(part[r][t], part[r][t + 64]),
                             fmaxf(part[r][t + 128], part[r][t + 192]));
            hi[r] = (unsigned short)(__float_as_uint(v0) >> 16);   // exact: bf16-valued
        }
        *(u16x8*)(void*)(orow + 512 + t * 8) = hi;
    }
}

// ================= fin2: out1 = fine + 0.1*(sigmoid-0.5) =================
__global__ void g_fin2(Params p) {
    const float* hacc2 = (const float*)(p.wsb + OFF_HACC2);
    int r = blockIdx.x * 256 + threadIdx.x;   // 0..4095
    #pragma unroll
    for (int ch = 0; ch < 3; ++ch) {
        float a = hacc2[(long)r * 4 + ch] + p.bx2[ch];
        p.out1[(long)r * 3 + ch] = p.out2[(long)r * 3 + ch]
                                 + 0.1f * (1.f / (1.f + expf(-a)) - 0.5f);
    }
}

// ================= launch =================
extern "C" void kernel_launch(void* const* d_in, const int* in_sizes, int n_in,
                              void* d_out, int out_size, void* d_ws, size_t ws_size,
                              hipStream_t stream) {
    Params p;
    p.z   = (const float*)d_in[0];
    p.W1a = (const float*)d_in[1];
    p.b1a = (const float*)d_in[2];
    p.W1b = (const float*)d_in[3];
    p.b1b = (const float*)d_in[4];
    p.W1c = (const float*)d_in[5];
    p.b1c = (const float*)d_in[6];
    p.Wx1 = (const float*)d_in[7];
    p.bx1 = (const float*)d_in[8];
    p.W2a = (const float*)d_in[9];
    p.b2a = (const float*)d_in[10];
    p.W2b = (const float*)d_in[11];
    p.b2b = (const float*)d_in[12];
    p.W2c = (const float*)d_in[13];
    p.b2c = (const float*)d_in[14];
    p.Wx2 = (const float*)d_in[15];
    p.bx2 = (const float*)d_in[16];
    p.wsb = (char*)d_ws;
    p.out0 = (float*)d_out;              // (2,1024,3)
    p.out1 = p.out0 + 2 * 1024 * 3;      // (2,2048,3)
    p.out2 = p.out1 + 2 * 2048 * 3;      // (2,2048,3) fine_points

    g_prep<<<2048, 256, 0, stream>>>(p);
    g_gemm1b<<<512, 256, 0, stream>>>(p);
    g_gemm1c<<<512, 256, 0, stream>>>(p);
    g_fin1<<<280, 256, 0, stream>>>(p);
    g_ball<<<dim3(2048, 2), 256, 0, stream>>>(p);
    g_gemm2a<<<512, 256, 0, stream>>>(p);
    g_gemm2b<<<512, 256, 0, stream>>>(p);
    g_gemm2c<<<512, 256, 0, stream>>>(p);
    g_fin2<<<16, 256, 0, stream>>>(p);
}